// Round 1
// baseline (727.585 us; speedup 1.0000x reference)
//
#include <hip/hip_runtime.h>
#include <hip/hip_fp16.h>
#include <cstdint>
#include <cstddef>

#define U_DIM 2048
#define D_DIM 2048
#define NH 16
#define DH 128
#define DFF 8192
#define EPS_RMS 1e-6f
#define ATTN_SCALE 0.088388347648318447f

typedef unsigned short u16;
typedef __attribute__((ext_vector_type(4))) float floatx4;
typedef __attribute__((ext_vector_type(8))) short shortx8;

__device__ __forceinline__ float bf2f(u16 u) {
  union { unsigned int i; float f; } v; v.i = ((unsigned int)u) << 16; return v.f;
}
__device__ __forceinline__ u16 f2bf(float f) {
  union { float f; unsigned int i; } v; v.f = f;
  return (u16)((v.i + 0x7fffu + ((v.i >> 16) & 1u)) >> 16);
}
__device__ __forceinline__ u16 f2h(float f) {
  __half h = __float2half_rn(f);
  union { __half h; u16 u; } c; c.h = h; return c.u;
}
__device__ __forceinline__ float h2f(u16 u) {
  union { __half h; u16 u; } c; c.u = u; return __half2float(c.h);
}

// fp32 -> bf16 bulk convert (n4 = n/4 float4 groups)
__global__ __launch_bounds__(256) void k_f2b(const float* __restrict__ in,
                                             u16* __restrict__ out, int n4) {
  int i = blockIdx.x * 256 + threadIdx.x;
  if (i >= n4) return;
  float4 f = reinterpret_cast<const float4*>(in)[i];
  ushort4 o;
  o.x = f2bf(f.x); o.y = f2bf(f.y); o.z = f2bf(f.z); o.w = f2bf(f.w);
  reinterpret_cast<ushort4*>(out)[i] = o;
}

// Permute adj fp32 [U,U] into frag-major fp16 tiles:
// adjp[(qt*16+kt)*16384 + (c16*128 + row)*8 + j] = adj[qt*128+row][kt*128+c16+16*j]
__global__ __launch_bounds__(256) void k_prep_bias(const float* __restrict__ adj,
                                                   u16* __restrict__ adjp) {
  const int tile = blockIdx.x;           // qt*16 + kt
  const int qt = tile >> 4, kt = tile & 15;
  const int t = threadIdx.x;
  const int c16 = t & 15, rblk = t >> 4; // 16 row-groups of 8
  u16* outt = adjp + (size_t)tile * 16384;
#pragma unroll
  for (int rr = 0; rr < 8; rr++) {
    int r = rblk * 8 + rr;
    const float* src = adj + (size_t)(qt * 128 + r) * U_DIM + kt * 128 + c16;
    ushort4 o0, o1;
    o0.x = f2h(src[0]);    o0.y = f2h(src[16]);  o0.z = f2h(src[32]);  o0.w = f2h(src[48]);
    o1.x = f2h(src[64]);   o1.y = f2h(src[80]);  o1.z = f2h(src[96]);  o1.w = f2h(src[112]);
    ushort4* dst = reinterpret_cast<ushort4*>(outt + ((size_t)c16 * 128 + r) * 8);
    dst[0] = o0; dst[1] = o1;
  }
}

// out4 = X4 + sum of 4 bf16 partials (+ bias[col]); fp32 out
__global__ __launch_bounds__(256) void k_reduce4(
    const u16* __restrict__ p0, const u16* __restrict__ p1,
    const u16* __restrict__ p2, const u16* __restrict__ p3,
    const float* __restrict__ X, const float* __restrict__ bias,
    float* __restrict__ out, int n4) {
  int i = blockIdx.x * 256 + threadIdx.x;
  if (i >= n4) return;
  ushort4 a = reinterpret_cast<const ushort4*>(p0)[i];
  ushort4 b = reinterpret_cast<const ushort4*>(p1)[i];
  ushort4 c = reinterpret_cast<const ushort4*>(p2)[i];
  ushort4 d = reinterpret_cast<const ushort4*>(p3)[i];
  float4 xv = reinterpret_cast<const float4*>(X)[i];
  float4 r;
  r.x = xv.x + bf2f(a.x) + bf2f(b.x) + bf2f(c.x) + bf2f(d.x);
  r.y = xv.y + bf2f(a.y) + bf2f(b.y) + bf2f(c.y) + bf2f(d.y);
  r.z = xv.z + bf2f(a.z) + bf2f(b.z) + bf2f(c.z) + bf2f(d.z);
  r.w = xv.w + bf2f(a.w) + bf2f(b.w) + bf2f(c.w) + bf2f(d.w);
  if (bias) {
    int col = (i * 4) & (D_DIM - 1);
    float4 bv = *reinterpret_cast<const float4*>(bias + col);
    r.x += bv.x; r.y += bv.y; r.z += bv.z; r.w += bv.w;
  }
  reinterpret_cast<float4*>(out)[i] = r;
}

// rmsnorm: one block per row of [U_DIM, D_DIM], fp32 in -> bf16 out
__global__ __launch_bounds__(256) void k_rmsnorm(const float* __restrict__ x,
                                                 const float* __restrict__ w,
                                                 u16* __restrict__ out) {
  const int row = blockIdx.x;
  const int t = threadIdx.x;
  const float4* xr = reinterpret_cast<const float4*>(x + (size_t)row * D_DIM);
  float4 a0 = xr[t], a1 = xr[t + 256];
  float ss = a0.x*a0.x + a0.y*a0.y + a0.z*a0.z + a0.w*a0.w
           + a1.x*a1.x + a1.y*a1.y + a1.z*a1.z + a1.w*a1.w;
#pragma unroll
  for (int off = 32; off > 0; off >>= 1) ss += __shfl_xor(ss, off);
  __shared__ float red[4];
  if ((t & 63) == 0) red[t >> 6] = ss;
  __syncthreads();
  float tot = red[0] + red[1] + red[2] + red[3];
  float r = rsqrtf(tot / (float)D_DIM + EPS_RMS);
  const float4* wr = reinterpret_cast<const float4*>(w);
  float4 w0 = wr[t], w1 = wr[t + 256];
  ushort4 o0, o1;
  o0.x = f2bf(a0.x * r * w0.x); o0.y = f2bf(a0.y * r * w0.y);
  o0.z = f2bf(a0.z * r * w0.z); o0.w = f2bf(a0.w * r * w0.w);
  o1.x = f2bf(a1.x * r * w1.x); o1.y = f2bf(a1.y * r * w1.y);
  o1.z = f2bf(a1.z * r * w1.z); o1.w = f2bf(a1.w * r * w1.w);
  ushort4* op = reinterpret_cast<ushort4*>(out + (size_t)row * D_DIM);
  op[t] = o0; op[t + 256] = o1;
}

// ---------------- GEMM core: C[128x128] += A[M,K] * B[N,K]^T ----------------
// Round-0 change: double-buffered LDS (2 x 8KB per matrix) with
// prefetch-after-barrier.  Per K-step: explicit s_waitcnt vmcnt(0) drains the
// DMAs issued LAST iteration, one barrier, then this iteration's prefetch is
// issued AFTER the barrier (so even a compiler-inserted drain at the barrier
// sees zero outstanding DMAs and costs nothing).  DMA latency for tile k+1
// overlaps ds_read+MFMA of tile k.  One barrier per K-step instead of two:
// at the barrier every wave has already consumed its ds_reads of the buffer
// the new prefetch targets (MFMA operands are waited before issue).
#define BKD 32

__device__ __forceinline__ void async16(u16* lds, const u16* g) {
  __builtin_amdgcn_global_load_lds(
      (__attribute__((address_space(1))) void*)(g),
      (__attribute__((address_space(3))) void*)(lds), 16, 0, 0);
}

__device__ __forceinline__ void gemm_core(
    const u16* __restrict__ A, int lda,
    const u16* __restrict__ B, int ldb,
    int K, int bm, int bn,
    u16* As, u16* Bs, floatx4 acc[4][4]) {
  const int t = threadIdx.x;
  const int wv = t >> 6, lane = t & 63;
  const int wr = wv >> 1, wc = wv & 1;
  const u16* Ag = A + (size_t)(bm + wv*32 + (lane >> 2)) * lda + (lane & 3) * 8;
  const u16* Bg = B + (size_t)(bn + wv*32 + (lane >> 2)) * ldb + (lane & 3) * 8;
  u16* AsW = As + wv * 1024;
  u16* BsW = Bs + wv * 1024;
  const int fr = lane & 15, kq = lane >> 4;
  const int aoff = (wr*64 + fr) * BKD + kq * 8;
  const int boff = (wc*64 + fr) * BKD + kq * 8;
  // prologue: stage K-tile 0 into buffer 0
  async16(AsW,       Ag);
  async16(AsW + 512, Ag + (size_t)16*lda);
  async16(BsW,       Bg);
  async16(BsW + 512, Bg + (size_t)16*ldb);
  int cur = 0;
  for (int k0 = 0; k0 < K; k0 += BKD) {
    asm volatile("s_waitcnt vmcnt(0)" ::: "memory");  // drain prev-iter prefetch
    __syncthreads();  // buf[cur] ready everywhere; prev-iter reads all consumed
    if (k0 + BKD < K) {  // prefetch buf[cur^1]; flies through the MFMAs below
      const int nb = (cur ^ 1) * 4096;
      async16(AsW + nb,       Ag + k0 + BKD);
      async16(AsW + nb + 512, Ag + (size_t)16*lda + k0 + BKD);
      async16(BsW + nb,       Bg + k0 + BKD);
      async16(BsW + nb + 512, Bg + (size_t)16*ldb + k0 + BKD);
    }
    const u16* ApF = As + cur * 4096 + aoff;
    const u16* BpF = Bs + cur * 4096 + boff;
    shortx8 af[4], bf[4];
#pragma unroll
    for (int i = 0; i < 4; i++) af[i] = *reinterpret_cast<const shortx8*>(ApF + i*16*BKD);
#pragma unroll
    for (int i = 0; i < 4; i++) bf[i] = *reinterpret_cast<const shortx8*>(BpF + i*16*BKD);
#pragma unroll
    for (int mi = 0; mi < 4; mi++)
#pragma unroll
      for (int ni = 0; ni < 4; ni++)
        acc[mi][ni] = __builtin_amdgcn_mfma_f32_16x16x32_bf16(af[mi], bf[ni], acc[mi][ni], 0, 0, 0);
    cur ^= 1;
  }
}

#define GEMM_PRELUDE                                              \
  __shared__ u16 As[2*128*BKD], Bs[2*128*BKD];                    \
  floatx4 acc[4][4];                                              \
  {                                                               \
    floatx4 zf = {0.f, 0.f, 0.f, 0.f};                            \
    for (int i = 0; i < 4; i++)                                   \
      for (int j = 0; j < 4; j++) acc[i][j] = zf;                 \
  }                                                               \
  const int bm = blockIdx.y * 128, bn = blockIdx.x * 128;

#define EPILOG_SETUP                                              \
  const int lane_ = threadIdx.x & 63;                             \
  const int wv_ = threadIdx.x >> 6;                               \
  const int row0 = (wv_ >> 1) * 64 + ((lane_ >> 4) << 2);         \
  const int col0 = (wv_ & 1) * 64 + (lane_ & 15);

// fused QKV: B = [wq; wk; wv] (6144 x 2048). Q,K stored [U,D]; V stored
// transposed as V^T [D, U] (per-head contiguous).
__global__ __launch_bounds__(256) void k_gemm_qkv(
    const u16* __restrict__ A, const u16* __restrict__ B,
    u16* __restrict__ Q, u16* __restrict__ Ko, u16* __restrict__ VT) {
  GEMM_PRELUDE;
  gemm_core(A, D_DIM, B, D_DIM, D_DIM, bm, bn, As, Bs, acc);
  EPILOG_SETUP;
  if (bn < 4096) {  // Q or K, normal store
    u16* C = (bn < 2048) ? Q : Ko;
    const int cb = (bn < 2048) ? bn : bn - 2048;
#pragma unroll
    for (int mt = 0; mt < 4; mt++)
#pragma unroll
      for (int i = 0; i < 4; i++) {
        u16* cr = C + (size_t)(bm + row0 + mt*16 + i) * D_DIM + cb + col0;
#pragma unroll
        for (int nt = 0; nt < 4; nt++) cr[nt*16] = f2bf(acc[mt][nt][i]);
      }
  } else {  // V, transposed store
    const int cb = bn - 4096;
#pragma unroll
    for (int mt = 0; mt < 4; mt++)
#pragma unroll
      for (int nt = 0; nt < 4; nt++) {
        int col = cb + col0 + nt*16;
        int row = bm + row0 + mt*16;
        ushort4 o;
        o.x = f2bf(acc[mt][nt][0]); o.y = f2bf(acc[mt][nt][1]);
        o.z = f2bf(acc[mt][nt][2]); o.w = f2bf(acc[mt][nt][3]);
        *reinterpret_cast<ushort4*>(VT + (size_t)col * U_DIM + row) = o;
      }
  }
}

// ---------------- Flash attention v2: 64-row Q tiles, 32-key tiles, --------
// double-buffered K/V with prefetch-at-top.  Grid (32, 16) = 512 blocks
// = 2 resident blocks/CU.  LDS 36 KB:
//   Ks[2]: [32][128] @0/@4096, Vs[2]: [128][32] @8192/@12288, Pb: [64][32] @16384
// Sync: B1 = explicit s_waitcnt(0)+barrier (drains the prefetch DMAs issued
// one iteration earlier).  B2 = plain __syncthreads (Pb visible before PV).
// Round-0 change: B3 removed — all Pb/Vs reads of iter t are consumed before
// any wave reaches B1 of iter t+1 (MFMA operands waited before issue), and
// iter-t+1's Pb writes / K-V prefetch writes occur only after B1, so B1 alone
// orders them.
__global__ __launch_bounds__(256) void k_flash(
    const u16* __restrict__ Q, const u16* __restrict__ K,
    const u16* __restrict__ VT, const u16* __restrict__ ADJP,
    u16* __restrict__ O) {
  __shared__ u16 smem[18432];  // 36 KB
  const int qt = blockIdx.x, gh = blockIdx.y;   // qt in [0,32)
  const int t = threadIdx.x, wv = t >> 6, lane = t & 63;
  const int fr = lane & 15, kq = lane >> 4;
  const int c4 = lane & 3, r4 = lane >> 2;

  const u16* gq = Q + (size_t)(qt * 64) * D_DIM + gh * DH;
  const u16* gk = K + gh * DH;
  const u16* gv = VT + (size_t)(gh * DH) * U_DIM;

  // stage Q [64][128] rot16 into smem[0..8192)
#pragma unroll
  for (int it = 0; it < 4; it++) {
    int row = wv * 16 + it * 4 + kq;
    int cg = (fr + row) & 15;
    async16(smem + row * 128 + fr * 8, gq + (size_t)row * D_DIM + cg * 8);
  }
  __builtin_amdgcn_s_waitcnt(0);
  __syncthreads();
  shortx8 qf[4];
#pragma unroll
  for (int ks = 0; ks < 4; ks++) {
    int row = wv * 16 + fr;
    int slot = ((ks * 4 + kq) - row) & 15;
    qf[ks] = *reinterpret_cast<const shortx8*>(smem + row * 128 + slot * 8);
  }
  __syncthreads();  // Q reads done; smem reusable

  floatx4 oacc[8];
  float mrow[4], lrow[4];
#pragma unroll
  for (int nt = 0; nt < 8; nt++) { floatx4 z = {0.f,0.f,0.f,0.f}; oacc[nt] = z; }
#pragma unroll
  for (int i = 0; i < 4; i++) { mrow[i] = -1e30f; lrow[i] = 0.f; }

  // stage K/V tile 0 into buffer 0
  {
    u16* Ks = smem; u16* Vs = smem + 8192;
#pragma unroll
    for (int it = 0; it < 2; it++) {
      int row = wv * 8 + it * 4 + kq;
      int cg = (fr + row) & 15;
      async16(Ks + row * 128 + fr * 8, gk + (size_t)row * D_DIM + cg * 8);
    }
#pragma unroll
    for (int it = 0; it < 2; it++) {
      int row = wv * 32 + it * 16 + r4;
      int cg = (c4 + (row >> 1)) & 3;
      async16(Vs + row * 32 + c4 * 8, gv + (size_t)row * U_DIM + cg * 8);
    }
  }

  u16* Pb = smem + 16384;
  for (int kt = 0; kt < 64; kt++) {
    const int cur = kt & 1;
    u16* Ks = smem + cur * 4096;
    u16* Vs = smem + 8192 + cur * 4096;
    __builtin_amdgcn_s_waitcnt(0);
    __syncthreads();  // B1: buf[cur] DMA complete, all waves arrived
    if (kt < 63) {    // prefetch buf[1-cur] for kt+1; flies through compute
      u16* Kn = smem + (1 - cur) * 4096;
      u16* Vn = smem + 8192 + (1 - cur) * 4096;
      const u16* gkn = gk + (size_t)((kt + 1) * 32) * D_DIM;
      const u16* gvn = gv + (kt + 1) * 32;
#pragma unroll
      for (int it = 0; it < 2; it++) {
        int row = wv * 8 + it * 4 + kq;
        int cg = (fr + row) & 15;
        async16(Kn + row * 128 + fr * 8, gkn + (size_t)row * D_DIM + cg * 8);
      }
#pragma unroll
      for (int it = 0; it < 2; it++) {
        int row = wv * 32 + it * 16 + r4;
        int cg = (c4 + (row >> 1)) & 3;
        async16(Vn + row * 32 + c4 * 8, gvn + (size_t)row * U_DIM + cg * 8);
      }
    }

    // S = Q K^T (32 keys)
    floatx4 sacc[2];
    { floatx4 z = {0.f,0.f,0.f,0.f}; sacc[0] = z; sacc[1] = z; }
#pragma unroll
    for (int ks = 0; ks < 4; ks++) {
      int slot0 = ((ks * 4 + kq) - fr) & 15;
      shortx8 kf0 = *reinterpret_cast<const shortx8*>(Ks + fr * 128 + slot0 * 8);
      int slot1 = ((ks * 4 + kq) - (16 + fr)) & 15;
      shortx8 kf1 = *reinterpret_cast<const shortx8*>(Ks + (16 + fr) * 128 + slot1 * 8);
      sacc[0] = __builtin_amdgcn_mfma_f32_16x16x32_bf16(qf[ks], kf0, sacc[0], 0, 0, 0);
      sacc[1] = __builtin_amdgcn_mfma_f32_16x16x32_bf16(qf[ks], kf1, sacc[1], 0, 0, 0);
    }

    // online softmax (C-layout: row = wv*16 + kq*4 + i, col = nt*16 + fr)
    const u16* bt = ADJP + ((size_t)(qt >> 1) * 16 + (kt >> 2)) * 16384 + (kt & 3) * 2;
#pragma unroll
    for (int i = 0; i < 4; i++) {
      int rl = wv * 16 + kq * 4 + i;
      int r128 = (qt & 1) * 64 + rl;
      ushort2 bh = *reinterpret_cast<const ushort2*>(bt + ((size_t)fr * 128 + r128) * 8);
      float s0 = sacc[0][i] * ATTN_SCALE + h2f(bh.x);
      float s1 = sacc[1][i] * ATTN_SCALE + h2f(bh.y);
      float mx = fmaxf(s0, s1);
      mx = fmaxf(mx, __shfl_xor(mx, 1));
      mx = fmaxf(mx, __shfl_xor(mx, 2));
      mx = fmaxf(mx, __shfl_xor(mx, 4));
      mx = fmaxf(mx, __shfl_xor(mx, 8));
      float mnew = fmaxf(mrow[i], mx);
      float alpha = __expf(mrow[i] - mnew);
      mrow[i] = mnew;
      float p0 = __expf(s0 - mnew), p1 = __expf(s1 - mnew);
      int slot0 = ((fr >> 3) - (rl >> 1)) & 3;
      Pb[rl * 32 + slot0 * 8 + (fr & 7)] = f2bf(p0);
      int slot1 = (((16 + fr) >> 3) - (rl >> 1)) & 3;
      Pb[rl * 32 + slot1 * 8 + (fr & 7)] = f2bf(p1);
      float ps = p0 + p1;
      ps += __shfl_xor(ps, 1);
      ps += __shfl_xor(ps, 2);
      ps += __shfl_xor(ps, 4);
      ps += __shfl_xor(ps, 8);
      lrow[i] = lrow[i] * alpha + ps;
#pragma unroll
      for (int nt = 0; nt < 8; nt++) oacc[nt][i] *= alpha;
    }
    __syncthreads();  // B2: Pb visible (lgkm only; prefetch stays in flight)

    // O += P V   (k = 32 -> one MFMA k-step)
    shortx8 pf;
    {
      int row = wv * 16 + fr;
      int slot = (kq - (row >> 1)) & 3;
      pf = *reinterpret_cast<const shortx8*>(Pb + row * 32 + slot * 8);
    }
#pragma unroll
    for (int nt = 0; nt < 8; nt++) {
      int row = nt * 16 + fr;
      int slot = (kq - (row >> 1)) & 3;
      shortx8 vf = *reinterpret_cast<const shortx8*>(Vs + row * 32 + slot * 8);
      oacc[nt] = __builtin_amdgcn_mfma_f32_16x16x32_bf16(pf, vf, oacc[nt], 0, 0, 0);
    }
    // (B3 removed: B1 of the next iteration orders Pb/Vs reads vs writes)
  }

  // epilogue: normalize by l, store bf16 to O[U, D] at head col block
#pragma unroll
  for (int i = 0; i < 4; i++) {
    int rl = wv * 16 + kq * 4 + i;
    float inv = 1.f / lrow[i];
    u16* orow = O + (size_t)(qt * 64 + rl) * D_DIM + gh * DH + fr;
#pragma unroll
    for (int nt = 0; nt < 8; nt++)
      orow[nt * 16] = f2bf(oacc[nt][i] * inv);
  }
}

// split-K GEMM into 4 bf16 partial buffers (grid.z = split)
__global__ __launch_bounds__(256) void k_gemm_splitk_part(
    const u16* __restrict__ A, int lda, const u16* __restrict__ B, int ldb,
    int Kc, u16* __restrict__ P, size_t pstride, int ldc) {
  GEMM_PRELUDE;
  const int koff = blockIdx.z * Kc;
  gemm_core(A + koff, lda, B + koff, ldb, Kc, bm, bn, As, Bs, acc);
  u16* Pz = P + (size_t)blockIdx.z * pstride;
  EPILOG_SETUP;
#pragma unroll
  for (int mt = 0; mt < 4; mt++)
#pragma unroll
    for (int i = 0; i < 4; i++) {
      u16* cr = Pz + (size_t)(bm + row0 + mt*16 + i) * ldc + bn + col0;
#pragma unroll
      for (int nt = 0; nt < 4; nt++) cr[nt*16] = f2bf(acc[mt][nt][i]);
    }
}

// fast gelu: tanh form via exp (abs err ~1e-3, well under threshold)
__device__ __forceinline__ float fast_gelu(float v) {
  float u = v * (0.79788456080286536f + 0.035677408136300125f * v * v);
  float tt = fminf(fmaxf(2.f * u, -40.f), 40.f);
  float e = __expf(tt);
  return 0.5f * v * (1.f + (e - 1.f) / (e + 1.f));
}

// gelu(A@B^T + bias) -> bf16
__global__ __launch_bounds__(256) void k_gemm_gelu(
    const u16* __restrict__ A, int lda, const u16* __restrict__ B, int ldb,
    int K, const float* __restrict__ bias, u16* __restrict__ C, int ldc) {
  GEMM_PRELUDE;
  gemm_core(A, lda, B, ldb, K, bm, bn, As, Bs, acc);
  EPILOG_SETUP;
#pragma unroll
  for (int mt = 0; mt < 4; mt++)
#pragma unroll
    for (int i = 0; i < 4; i++) {
      size_t off = (size_t)(bm + row0 + mt*16 + i) * ldc + bn + col0;
#pragma unroll
      for (int nt = 0; nt < 4; nt++) {
        float v = acc[mt][nt][i] + bias[bn + col0 + nt*16];
        C[off + nt*16] = f2bf(fast_gelu(v));
      }
    }
}

// Workspace timeline (MB offsets, peak 104):
//  A: hb@0-8, wob@48-56, wqkv@56-80, adjp@32-40 (prep)
//  B: qkv -> qb@8-16 kb@16-24 vtb@24-32
//  C: flash -> aob@40-48  (reads qb,kb,vtb,adjp)
//  D: out-proj partials opp@8-40 (qb/kb/vtb/adjp dead); reduce -> out = x + sum
//  E: h2b@0-8, wub@8-40 (opp dead), ffb@40-72 (aob/wob/wqkv dead), wdb@72-104,
//     down partials dpp@8-40 (wub dead after gelu); reduce -> out += sum + b_down
extern "C" void kernel_launch(void* const* d_in, const int* in_sizes, int n_in,
                              void* d_out, int out_size, void* d_ws, size_t ws_size,
                              hipStream_t stream) {
  (void)in_sizes; (void)n_in; (void)out_size; (void)ws_size;
  const float* x      = (const float*)d_in[0];
  const float* adj    = (const float*)d_in[1];
  const float* n1w    = (const float*)d_in[2];
  const float* n2w    = (const float*)d_in[3];
  const float* wq     = (const float*)d_in[4];
  const float* wk     = (const float*)d_in[5];
  const float* wv     = (const float*)d_in[6];
  const float* wo     = (const float*)d_in[7];
  const float* w_up   = (const float*)d_in[8];
  const float* b_up   = (const float*)d_in[9];
  const float* w_down = (const float*)d_in[10];
  const float* b_down = (const float*)d_in[11];
  float* out = (float*)d_out;
  char* ws = (char*)d_ws;
  const size_t MB = 1u << 20;
  u16* hb   = (u16*)(ws + 0*MB);
  u16* qb   = (u16*)(ws + 8*MB);
  u16* kb   = (u16*)(ws + 16*MB);
  u16* vtb  = (u16*)(ws + 24*MB);
  u16* adjp = (u16*)(ws + 32*MB);
  u16* aob  = (u16*)(ws + 40*MB);
  u16* wob  = (u16*)(ws + 48*MB);
  u16* wqkv = (u16*)(ws + 56*MB);
  u16* opp  = (u16*)(ws + 8*MB);   // 4 x 8MB out-proj partials
  u16* h2b  = (u16*)(ws + 0*MB);
  u16* wub  = (u16*)(ws + 8*MB);
  u16* ffb  = (u16*)(ws + 40*MB);
  u16* wdb  = (u16*)(ws + 72*MB);
  u16* dpp  = (u16*)(ws + 8*MB);   // 4 x 8MB FFN-down partials (overlays wub)

  dim3 blk(256);
  const int n4d = (D_DIM * D_DIM) / 4;
  const int n4f = (DFF * D_DIM) / 4;
  const size_t szd = (size_t)D_DIM * D_DIM;

  // phase A: weight conversion + bias permute + norm1
  k_f2b<<<(n4d + 255) / 256, blk, 0, stream>>>(wq, wqkv, n4d);
  k_f2b<<<(n4d + 255) / 256, blk, 0, stream>>>(wk, wqkv + szd, n4d);
  k_f2b<<<(n4d + 255) / 256, blk, 0, stream>>>(wv, wqkv + 2*szd, n4d);
  k_f2b<<<(n4d + 255) / 256, blk, 0, stream>>>(wo, wob, n4d);
  k_prep_bias<<<256, blk, 0, stream>>>(adj, adjp);
  k_rmsnorm<<<U_DIM, blk, 0, stream>>>(x, n1w, hb);

  // phase B: fused QKV (768 blocks)
  k_gemm_qkv<<<dim3(48, 16), blk, 0, stream>>>(hb, wqkv, qb, kb, vtb);

  // phase C: flash attention (512 blocks, 2/CU) -> aob
  k_flash<<<dim3(32, 16), blk, 0, stream>>>(qb, kb, vtb, adjp, aob);

  // phase D: out-projection split-K4 -> partials; reduce adds residual x
  k_gemm_splitk_part<<<dim3(16, 16, 4), blk, 0, stream>>>(
      aob, D_DIM, wob, D_DIM, D_DIM/4, opp, szd, D_DIM);
  k_reduce4<<<(n4d + 255) / 256, blk, 0, stream>>>(
      opp, opp + szd, opp + 2*szd, opp + 3*szd, x, nullptr, out, n4d);

  // phase E: FFN
  k_rmsnorm<<<U_DIM, blk, 0, stream>>>(out, n2w, h2b);
  k_f2b<<<(n4f + 255) / 256, blk, 0, stream>>>(w_up, wub, n4f);
  k_gemm_gelu<<<dim3(64, 16), blk, 0, stream>>>(h2b, D_DIM, wub, D_DIM, D_DIM,
                                                b_up, ffb, DFF);
  k_f2b<<<(n4f + 255) / 256, blk, 0, stream>>>(w_down, wdb, n4f);
  k_gemm_splitk_part<<<dim3(16, 16, 4), blk, 0, stream>>>(
      ffb, DFF, wdb, DFF, DFF/4, dpp, szd, D_DIM);
  k_reduce4<<<(n4d + 255) / 256, blk, 0, stream>>>(
      dpp, dpp + szd, dpp + 2*szd, dpp + 3*szd, out, b_down, out, n4d);
}